// Round 6
// baseline (194.551 us; speedup 1.0000x reference)
//
#include <hip/hip_runtime.h>
#include <hip/hip_bf16.h>

#define P_ADC 64
#define M_SEN 256
#define B_BLK 32
#define BATCHN 4096

// Derived GEMM: Out[R=131072][128] = X[R][512] * W[512][128], W[k][p] = A[p][k]
#define GK 512
#define GN 128
#define GR (BATCHN * B_BLK)   // 131072 rows

typedef float  f32x4  __attribute__((ext_vector_type(4)));
typedef __bf16 bf16x8 __attribute__((ext_vector_type(8)));
typedef unsigned int u32x4 __attribute__((ext_vector_type(4)));

// ---------------------------------------------------------------------------
// Single fused kernel.
//  - Each block builds the t<8 HALF of W's MFMA fragments in LDS (64 KB)
//    from p_values directly (sinpif/cospif), no global W array at all.
//  - Fragment layout: lw[t][f][lane][j], t=0..7, f=0..7:
//      W[k][n], n = f*16+(lane&15), g=lane>>4, k = t*32+(j>>2)*16+g*4+(j&3)
//      (k-slot permutation applied identically to the X fragment, so the
//      MFMA contraction is unchanged; makes X loads full-64B-line)
//    W[k][n]=A[n][k]: (n<64,k<256)=cos,(n>=64,k<256)=sin,
//                     (n<64,k>=256)=-sin,(n>=64,k>=256)=cos,
//      ang = -2pi*pv[n&63]*(k&255)/256 = pi*(pv*.(k&255)*(-1/128))
//    Symmetry (k->k+256): frag(t+8,f)= -frag(t,f+4) [f<4], = +frag(t,f-4) [f>=4]
//  - 512 thr = 8 waves, wave = 16 rows x 128 cols (acc[8]); 2 blocks/CU
//    (64KB LDS, <=128 VGPR via __launch_bounds__(512,4)); grid = 1024.
//  - X prefetched 6 t-blocks deep, first 6 issued BEFORE the W build so HBM
//    streaming overlaps the VALU-only fragment construction.
//  - Swapped MFMA operands (A=W from LDS, B=X): D reg r = out col -> f32x4
//    nontemporal stores.
// ---------------------------------------------------------------------------
__global__ __launch_bounds__(512, 4) void analog_fused(const float* __restrict__ X,
                                                       const float* __restrict__ pv,
                                                       float* __restrict__ out) {
    __shared__ __bf16 lw[8 * 8 * 64 * 8];   // 32768 bf16 = 64 KB

    const int tid  = threadIdx.x;
    const int lane = tid & 63;
    const int wave = tid >> 6;        // 0..7
    const int lr   = lane & 15;       // X row within 16-row stripe
    const int g    = lane >> 4;       // k sub-group

    const long rowbase = (long)blockIdx.x * 128 + (long)wave * 16;
    const float* xp = X + (rowbase + lr) * (long)GK + g * 4;

    // ---- issue first 6 X t-block loads (HBM starts flowing immediately) ----
    f32x4 pxa[6], pxb[6];
#pragma unroll
    for (int t = 0; t < 6; ++t) {
        pxa[t] = __builtin_nontemporal_load((const f32x4*)(xp + t * 32));
        pxb[t] = __builtin_nontemporal_load((const f32x4*)(xp + t * 32 + 16));
    }

    // ---- build t<8 W-fragment half in LDS (VALU only, overlaps loads) ----
#pragma unroll
    for (int i = 0; i < 8; ++i) {
        int slot = i * 512 + tid;          // 4096 fragment slots
        int sl = slot & 63, sf = (slot >> 6) & 7, st = slot >> 9;
        int n  = sf * 16 + (sl & 15);
        int sg = sl >> 4;
        float pq = pv[n & 63];
        bool ph  = (n >= 64);
        bf16x8 v;
#pragma unroll
        for (int j = 0; j < 8; ++j) {
            int k = st * 32 + ((j >> 2) << 4) + sg * 4 + (j & 3);   // k < 256
            float arg = pq * (float)k * (-0.0078125f);              // ang / pi
            float a = ph ? sinpif(arg) : cospif(arg);
            v[j] = (__bf16)a;
        }
        *(bf16x8*)(lw + (size_t)slot * 8) = v;
    }
    __syncthreads();

    const bf16x8* wp = (const bf16x8*)lw + lane;   // + (t*8 + f)*64, t<8

    f32x4 acc[8];
#pragma unroll
    for (int f = 0; f < 8; ++f) acc[f] = (f32x4)0.0f;

#pragma unroll
    for (int t = 0; t < 16; ++t) {
        f32x4 xa = pxa[t % 6];
        f32x4 xb = pxb[t % 6];
        if (t + 6 < 16) {   // static (unrolled): rolling 6-deep prefetch
            pxa[t % 6] = __builtin_nontemporal_load((const f32x4*)(xp + (t + 6) * 32));
            pxb[t % 6] = __builtin_nontemporal_load((const f32x4*)(xp + (t + 6) * 32 + 16));
        }

        bf16x8 b;
#pragma unroll
        for (int j = 0; j < 4; ++j) { b[j] = (__bf16)xa[j]; b[4 + j] = (__bf16)xb[j]; }

        if (t < 8) {
#pragma unroll
            for (int f = 0; f < 8; ++f) {
                bf16x8 w = wp[(t * 8 + f) * 64];
                acc[f] = __builtin_amdgcn_mfma_f32_16x16x32_bf16(w, b, acc[f], 0, 0, 0);
            }
        } else {
            // frag(t,f) = -frag(t-8,f+4) for f<4 ; +frag(t-8,f-4) for f>=4
            u32x4 u = __builtin_bit_cast(u32x4, b);
#pragma unroll
            for (int j = 0; j < 4; ++j) u[j] ^= 0x80008000u;
            bf16x8 bneg = __builtin_bit_cast(bf16x8, u);
#pragma unroll
            for (int f = 0; f < 4; ++f) {
                bf16x8 w = wp[((t - 8) * 8 + f + 4) * 64];
                acc[f] = __builtin_amdgcn_mfma_f32_16x16x32_bf16(w, bneg, acc[f], 0, 0, 0);
            }
#pragma unroll
            for (int f = 4; f < 8; ++f) {
                bf16x8 w = wp[((t - 8) * 8 + f - 4) * 64];
                acc[f] = __builtin_amdgcn_mfma_f32_16x16x32_bf16(w, b, acc[f], 0, 0, 0);
            }
        }
    }

    // lane stores row rowbase+lr, cols f*16 + g*4 .. +3
    float* op = out + (rowbase + lr) * (long)GN + g * 4;
#pragma unroll
    for (int f = 0; f < 8; ++f)
        __builtin_nontemporal_store(acc[f], (f32x4*)(op + f * 16));
}

extern "C" void kernel_launch(void* const* d_in, const int* in_sizes, int n_in,
                              void* d_out, int out_size, void* d_ws, size_t ws_size,
                              hipStream_t stream) {
    const float* x  = (const float*)d_in[0];
    const float* pv = (const float*)d_in[1];
    float* out      = (float*)d_out;

    hipLaunchKernelGGL(analog_fused, dim3(GR / 128), dim3(512), 0, stream, x, pv, out);
}

// Round 7
// 185.971 us; speedup vs baseline: 1.0461x; 1.0461x over previous
//
#include <hip/hip_runtime.h>
#include <hip/hip_bf16.h>

#define P_ADC 64
#define M_SEN 256
#define B_BLK 32
#define BATCHN 4096

// Derived GEMM: Out[R=131072][128] = X[R][512] * W[512][128], W[k][p] = A[p][k]
#define GK 512
#define GN 128
#define GR (BATCHN * B_BLK)   // 131072 rows

typedef float  f32x4  __attribute__((ext_vector_type(4)));
typedef __bf16 bf16x8 __attribute__((ext_vector_type(8)));
typedef unsigned int u32x4 __attribute__((ext_vector_type(4)));

// ---------------------------------------------------------------------------
// Kernel 1: build the t<8 HALF of W in MFMA fragment order (64 KB).
// wfrag[t][f][lane][j], t=0..7, f=0..7:
//   W[k][n], n = f*16+(lane&15), g=lane>>4, k = t*32+(j>>2)*16+g*4+(j&3)
//   (k-slot permutation applied identically to the X fragment -> contraction
//   unchanged; makes X loads cover full 64B lines)
// W[k][n]=A[n][k]: k<256: n<64 -> cos, n>=64 -> sin (ang=-2pi*pv[n&63]*k/256)
// Symmetry (k->k+256 flips quadrant): frag(t+8,f) = -frag(t,f+4) [f<4],
//                                     frag(t+8,f) = +frag(t,f-4) [f>=4]
// ---------------------------------------------------------------------------
__global__ void build_w_frags(const float* __restrict__ pv, __bf16* __restrict__ wfrag) {
    int tid = blockIdx.x * blockDim.x + threadIdx.x;
    if (tid >= 8 * 8 * 64) return;
    int lane = tid & 63;
    int f    = (tid >> 6) & 7;
    int t    = tid >> 9;          // 0..7
    int n    = f * 16 + (lane & 15);
    int g    = lane >> 4;
    bool ph  = (n >= 64);
    float pq = pv[n & 63];
    const float step = -0.02454369260617025967f; // -2*pi/256
    bf16x8 v;
#pragma unroll
    for (int j = 0; j < 8; ++j) {
        int k  = t * 32 + ((j >> 2) << 4) + g * 4 + (j & 3);   // k < 256
        float ang = pq * (float)k * step;
        float s, c;
        sincosf(ang, &s, &c);
        v[j] = (__bf16)(ph ? s : c);
    }
    *(bf16x8*)(wfrag + (size_t)tid * 8) = v;
}

// ---------------------------------------------------------------------------
// Kernel 2: 512 thr = 8 waves; wave = 16 rows x 128 cols (acc[8] like R3).
// LDS = 64 KB (t<8 frag half) -> 2 blocks/CU, 16 waves/CU; the two resident
// blocks stagger their stage/barrier/epilogue phases. Grid = 1024.
// t>=8 reuses t<8 frags via the signed symmetry (negate packed X fragment
// for f<4, swap f+-4). Swapped MFMA operands: A=W(LDS), B=X ->
// D reg r = out col -> f32x4 nontemporal stores.
// No explicit prefetch arrays: compiler schedules X loads (R3-proven).
// ---------------------------------------------------------------------------
__global__ __launch_bounds__(512, 4) void analog_gemm(const float* __restrict__ X,
                                                      const __bf16* __restrict__ W,
                                                      float* __restrict__ out) {
    __shared__ __bf16 lw[8 * 8 * 64 * 8];   // 32768 bf16 = 64 KB

    const int tid = threadIdx.x;

    // Stage t<8 frags global->LDS: 4096 x 16B chunks, 512 thr x 8 each.
    {
        const f32x4* src = (const f32x4*)W;
        f32x4* dst = (f32x4*)lw;
#pragma unroll
        for (int i = 0; i < 8; ++i)
            dst[i * 512 + tid] = src[i * 512 + tid];
    }
    __syncthreads();

    const int lane = tid & 63;
    const int wave = tid >> 6;        // 0..7
    const int lr   = lane & 15;
    const int g    = lane >> 4;

    const long rowbase = (long)blockIdx.x * 128 + (long)wave * 16;
    const float* xp = X + (rowbase + lr) * (long)GK + g * 4;
    const bf16x8* wp = (const bf16x8*)lw + lane;   // + (t*8 + f)*64, t<8

    f32x4 acc[8];
#pragma unroll
    for (int f = 0; f < 8; ++f) acc[f] = (f32x4)0.0f;

#pragma unroll
    for (int t = 0; t < 8; ++t) {
        f32x4 xa = *(const f32x4*)(xp + t * 32);
        f32x4 xb = *(const f32x4*)(xp + t * 32 + 16);
        bf16x8 b;
#pragma unroll
        for (int j = 0; j < 4; ++j) { b[j] = (__bf16)xa[j]; b[4 + j] = (__bf16)xb[j]; }
#pragma unroll
        for (int f = 0; f < 8; ++f) {
            bf16x8 w = wp[(t * 8 + f) * 64];
            acc[f] = __builtin_amdgcn_mfma_f32_16x16x32_bf16(w, b, acc[f], 0, 0, 0);
        }
    }

#pragma unroll
    for (int t = 8; t < 16; ++t) {
        f32x4 xa = *(const f32x4*)(xp + t * 32);
        f32x4 xb = *(const f32x4*)(xp + t * 32 + 16);
        bf16x8 b;
#pragma unroll
        for (int j = 0; j < 4; ++j) { b[j] = (__bf16)xa[j]; b[4 + j] = (__bf16)xb[j]; }
        u32x4 u = __builtin_bit_cast(u32x4, b);
#pragma unroll
        for (int j = 0; j < 4; ++j) u[j] ^= 0x80008000u;
        bf16x8 bneg = __builtin_bit_cast(bf16x8, u);
#pragma unroll
        for (int f = 0; f < 4; ++f) {
            bf16x8 w = wp[((t - 8) * 8 + f + 4) * 64];
            acc[f] = __builtin_amdgcn_mfma_f32_16x16x32_bf16(w, bneg, acc[f], 0, 0, 0);
        }
#pragma unroll
        for (int f = 4; f < 8; ++f) {
            bf16x8 w = wp[((t - 8) * 8 + f - 4) * 64];
            acc[f] = __builtin_amdgcn_mfma_f32_16x16x32_bf16(w, b, acc[f], 0, 0, 0);
        }
    }

    // lane stores row rowbase+lr, cols f*16 + g*4 .. +3
    float* op = out + (rowbase + lr) * (long)GN + g * 4;
#pragma unroll
    for (int f = 0; f < 8; ++f)
        __builtin_nontemporal_store(acc[f], (f32x4*)(op + f * 16));
}

extern "C" void kernel_launch(void* const* d_in, const int* in_sizes, int n_in,
                              void* d_out, int out_size, void* d_ws, size_t ws_size,
                              hipStream_t stream) {
    const float* x  = (const float*)d_in[0];
    const float* pv = (const float*)d_in[1];
    float* out      = (float*)d_out;
    __bf16* wfrag   = (__bf16*)d_ws;   // 8*8*64*8*2 = 65536 bytes used

    hipLaunchKernelGGL(build_w_frags, dim3(16), dim3(256), 0, stream, pv, wfrag);
    hipLaunchKernelGGL(analog_gemm, dim3(GR / 128), dim3(512), 0, stream, x, wfrag, out);
}

// Round 8
// 63.580 us; speedup vs baseline: 3.0599x; 2.9250x over previous
//
#include <hip/hip_runtime.h>
#include <hip/hip_bf16.h>

#define P_ADC 64
#define M_SEN 256
#define B_BLK 32
#define BATCHN 4096

// Derived GEMM: Out[R=131072][128] = X[R][512] * W[512][128], W[k][p] = A[p][k]
#define GK 512
#define GN 128
#define GR (BATCHN * B_BLK)   // 131072 rows

typedef float  f32x4  __attribute__((ext_vector_type(4)));
typedef __bf16 bf16x8 __attribute__((ext_vector_type(8)));
typedef unsigned int u32x4 __attribute__((ext_vector_type(4)));

// ---------------------------------------------------------------------------
// Kernel 1: build the k<256 HALF of W in MFMA fragment order (64 KB).
// wfrag[t][f][lane][j], t=0..7, f=0..7:
//   W[k][n], n = f*16+(lane&15), g=lane>>4, k = t*32+(j>>2)*16+g*4+(j&3)
//   (k-slot permutation applied identically to the X fragment -> contraction
//   unchanged; makes X loads cover full 64B lines)
// W[k][n]=A[n][k]: k<256: n<64 -> cos, n>=64 -> sin (ang=-2pi*pv[n&63]*k/256)
// Symmetry (k->k+256 flips quadrant): frag_full(t+8,f) = -frag(t,f+4) [f<4],
//                                     frag_full(t+8,f) = +frag(t,f-4) [f>=4]
// ---------------------------------------------------------------------------
__global__ void build_w_frags(const float* __restrict__ pv, __bf16* __restrict__ wfrag) {
    int tid = blockIdx.x * blockDim.x + threadIdx.x;
    if (tid >= 8 * 8 * 64) return;
    int lane = tid & 63;
    int f    = (tid >> 6) & 7;
    int t    = tid >> 9;          // 0..7
    int n    = f * 16 + (lane & 15);
    int g    = lane >> 4;
    bool ph  = (n >= 64);
    float pq = pv[n & 63];
    const float step = -0.02454369260617025967f; // -2*pi/256
    bf16x8 v;
#pragma unroll
    for (int j = 0; j < 8; ++j) {
        int k  = t * 32 + ((j >> 2) << 4) + g * 4 + (j & 3);   // k < 256
        float ang = pq * (float)k * step;
        float s, c;
        sincosf(ang, &s, &c);
        v[j] = (__bf16)(ph ? s : c);
    }
    *(bf16x8*)(wfrag + (size_t)tid * 8) = v;
}

// ---------------------------------------------------------------------------
// Kernel 2: 512 thr = 8 waves; wave = 16 rows x 128 cols (acc[8]).
// LDS = 64 KB -> 2 blocks/CU, 16 waves/CU. Grid = 1024.
// INTERLEAVED symmetry: one loop over t=0..7 handles K-steps t AND t+8 so
// each LDS fragment is read ONCE and consumed by exactly 2 adjacent MFMAs
// (prevents the R7 CSE register explosion / spill):
//   acc[f]   += frag(t,f) . b_t
//   acc[f+4] += frag(t,f) . b_{t+8}        (f<4)
//   acc[f-4] += frag(t,f) . (-b_{t+8})     (f>=4, sign folded into packed X)
// Swapped MFMA operands: A=W(LDS), B=X -> D reg r = out col -> f32x4 stores.
// ---------------------------------------------------------------------------
__global__ __launch_bounds__(512, 4) void analog_gemm(const float* __restrict__ X,
                                                      const __bf16* __restrict__ W,
                                                      float* __restrict__ out) {
    __shared__ __bf16 lw[8 * 8 * 64 * 8];   // 32768 bf16 = 64 KB

    const int tid = threadIdx.x;

    // Stage frags global->LDS: 4096 x 16B chunks, 512 thr x 8 each.
    {
        const f32x4* src = (const f32x4*)W;
        f32x4* dst = (f32x4*)lw;
#pragma unroll
        for (int i = 0; i < 8; ++i)
            dst[i * 512 + tid] = src[i * 512 + tid];
    }
    __syncthreads();

    const int lane = tid & 63;
    const int wave = tid >> 6;        // 0..7
    const int lr   = lane & 15;
    const int g    = lane >> 4;

    const long rowbase = (long)blockIdx.x * 128 + (long)wave * 16;
    const float* xp = X + (rowbase + lr) * (long)GK + g * 4;
    const bf16x8* wp = (const bf16x8*)lw + lane;   // + (t*8 + f)*64, t<8

    f32x4 acc[8];
#pragma unroll
    for (int f = 0; f < 8; ++f) acc[f] = (f32x4)0.0f;

#pragma unroll
    for (int t = 0; t < 8; ++t) {
        f32x4 xa = *(const f32x4*)(xp + t * 32);
        f32x4 xb = *(const f32x4*)(xp + t * 32 + 16);
        f32x4 xc = *(const f32x4*)(xp + (t + 8) * 32);
        f32x4 xd = *(const f32x4*)(xp + (t + 8) * 32 + 16);

        bf16x8 b0, b1;
#pragma unroll
        for (int j = 0; j < 4; ++j) {
            b0[j] = (__bf16)xa[j];  b0[4 + j] = (__bf16)xb[j];
            b1[j] = (__bf16)xc[j];  b1[4 + j] = (__bf16)xd[j];
        }
        u32x4 u = __builtin_bit_cast(u32x4, b1);
#pragma unroll
        for (int j = 0; j < 4; ++j) u[j] ^= 0x80008000u;
        bf16x8 b1n = __builtin_bit_cast(bf16x8, u);

#pragma unroll
        for (int f = 0; f < 8; ++f) {
            bf16x8 w = wp[(t * 8 + f) * 64];
            acc[f] = __builtin_amdgcn_mfma_f32_16x16x32_bf16(w, b0, acc[f], 0, 0, 0);
            if (f < 4)
                acc[f + 4] = __builtin_amdgcn_mfma_f32_16x16x32_bf16(w, b1, acc[f + 4], 0, 0, 0);
            else
                acc[f - 4] = __builtin_amdgcn_mfma_f32_16x16x32_bf16(w, b1n, acc[f - 4], 0, 0, 0);
        }
    }

    // lane stores row rowbase+lr, cols f*16 + g*4 .. +3
    float* op = out + (rowbase + lr) * (long)GN + g * 4;
#pragma unroll
    for (int f = 0; f < 8; ++f)
        __builtin_nontemporal_store(acc[f], (f32x4*)(op + f * 16));
}

extern "C" void kernel_launch(void* const* d_in, const int* in_sizes, int n_in,
                              void* d_out, int out_size, void* d_ws, size_t ws_size,
                              hipStream_t stream) {
    const float* x  = (const float*)d_in[0];
    const float* pv = (const float*)d_in[1];
    float* out      = (float*)d_out;
    __bf16* wfrag   = (__bf16*)d_ws;   // 8*8*64*8*2 = 65536 bytes used

    hipLaunchKernelGGL(build_w_frags, dim3(16), dim3(256), 0, stream, pv, wfrag);
    hipLaunchKernelGGL(analog_gemm, dim3(GR / 128), dim3(512), 0, stream, x, wfrag, out);
}